// Round 7
// baseline (2434.624 us; speedup 1.0000x reference)
//
#include <hip/hip_runtime.h>
#include <hip/hip_bf16.h>

// ---------------- problem constants ----------------
#define BSZ 64
#define SEQ 2048
#define HD  256
#define ND  256
#define BS_TOK (BSZ*SEQ)          // 131072 tokens
#define NCAND 101
#define EPS 1e-5f

using bf16 = __hip_bfloat16;
typedef unsigned short u16;
typedef unsigned int   u32;
typedef __attribute__((ext_vector_type(8))) short short8v;   // 8 bf16 (4 VGPRs)
typedef __attribute__((ext_vector_type(4))) float f32x4;

__device__ __forceinline__ float clampf(float v, float c) { return fminf(fmaxf(v, -c), c); }

// fp32 -> (hi,lo) bf16 split: x ~= hi + lo to ~2^-17 rel
__device__ __forceinline__ void split_bf(float x, u16& h, u16& l) {
  u32 u = __float_as_uint(x);
  h = (u16)(u >> 16);
  float d = x - __uint_as_float(u & 0xffff0000u);
  l = (u16)(__float_as_uint(d) >> 16);
}
__device__ __forceinline__ u32 pack32(float x) {
  u16 h, l; split_bf(x, h, l);
  return (u32)h | ((u32)l << 16);
}
__device__ __forceinline__ float unp32(u32 p) {
  return __uint_as_float(p << 16) + __uint_as_float(p & 0xffff0000u);
}

// Packed activation layout P(K): element (row,k) is one u32 (hi | lo<<16) at
//   u32 offset ((p*(K/8) + (k>>3))*16 + (row&15))*8 + (k&7),  p = row>>4.
// A wave MFMA-fragment load (16 rows x 8 k per lane) is 1KB contiguous.

// ---------------- workspace layout ----------------
static constexpr size_t MiB = 1024*1024;
static constexpr size_t OFF_X    = 0;                         // Xf fp32 [BS_TOK,256]
static constexpr size_t OFF_PR   = 128*MiB;                   // fp32[1024]: abr[512] abi[512]
static constexpr size_t OFF_WB   = OFF_PR + 4096;             // u16 weight planes, 2 MiB used
static constexpr size_t OFF_XLR  = OFF_WB + 4*MiB;
static constexpr size_t OFF_XLI  = OFF_XLR + 65536;
static constexpr size_t OFF_YL   = OFF_XLI + 65536;
static constexpr size_t OFF_XF   = OFF_YL  + 65536;
static constexpr size_t OFF_CH   = 136*MiB;                   // HbP P(256) 2*CB MiB, SbP P(512) 4*CB MiB

// wb u16 offsets (hi/lo planes, k-major per output col)
static constexpr int WB_BB0H = 0,       WB_BB0L = 131072;     // [512 cols][K=256]
static constexpr int WB_BB1H = 262144,  WB_BB1L = 393216;
static constexpr int WB_WSH  = 524288,  WB_WSL  = 655360;     // [256 cols][K=512]
static constexpr int WB_W1H  = 786432,  WB_W1L  = 851968;     // [256 cols][K=256]
static constexpr int WB_W2H  = 917504,  WB_W2L  = 983040;

// ---------------- param pack ----------------
__global__ __launch_bounds__(256) void pack_k(
    const float* __restrict__ lar, const float* __restrict__ aim, const float* __restrict__ lstep,
    const float* __restrict__ C0, const float* __restrict__ W1, const float* __restrict__ W2,
    const float* __restrict__ Bf,
    float* __restrict__ pr, u16* __restrict__ wb)
{
  int gid = blockIdx.x*256 + threadIdx.x;   // grid 256 -> 65536
  if (gid < 512) {
    int blk = gid >> 8;
    float step = expf(clampf(lstep[blk], 10.f));
    float ar = -expf(clampf(lar[gid], 20.f));
    float ai = aim[gid];
    float er = expf(fminf(ar*step, 0.f));
    pr[gid]       = er * cosf(ai*step);
    pr[512 + gid] = er * sinf(ai*step);
  }
  int r = gid >> 8, c = gid & 255;          // r = out col (n or h), c = k index
  u16 h, l;
#pragma unroll
  for (int blk = 0; blk < 2; ++blk) {
    float step = expf(clampf(lstep[blk], 10.f));
    float ar = -expf(clampf(lar[blk*256 + c], 20.f));
    float ai = aim[blk*256 + c];
    float er  = expf(fminf(ar*step, 0.f));
    float abr = er * cosf(ai*step);
    float abi = er * sinf(ai*step);
    float den = ar*ar + ai*ai;
    float tr = abr - 1.f, ti = abi;
    float cr = (tr*ar + ti*ai) / den;
    float ci = (ti*ar - tr*ai) / den;
    float bv = Bf[blk*65536 + r*256 + c];
    u16* Bh = wb + (blk ? WB_BB1H : WB_BB0H);
    u16* Bl = wb + (blk ? WB_BB1L : WB_BB0L);
    split_bf(cr * bv, h, l); Bh[r*256 + c] = h;         Bl[r*256 + c] = l;
    split_bf(ci * bv, h, l); Bh[(256+r)*256 + c] = h;   Bl[(256+r)*256 + c] = l;
  }
  // Wstk: out col = h (r), k = [n | 256+n], K=512
  split_bf( C0[(size_t)(r*256 + c)*2    ], h, l);
  wb[WB_WSH + r*512 + c] = h;        wb[WB_WSL + r*512 + c] = l;
  split_bf(-C0[(size_t)(r*256 + c)*2 + 1], h, l);
  wb[WB_WSH + r*512 + 256 + c] = h;  wb[WB_WSL + r*512 + 256 + c] = l;
  // W1T/W2T: out col = n (r), k = c
  split_bf(W1[c*256 + r], h, l); wb[WB_W1H + r*256 + c] = h; wb[WB_W1L + r*256 + c] = l;
  split_bf(W2[c*256 + r], h, l); wb[WB_W2H + r*256 + c] = h; wb[WB_W2L + r*256 + c] = l;
}

// ---------------- fused embed + first LayerNorm (+ D*u residual) ----------------
// 1024 thr = 16 waves = 16 rows (one P-panel). LN per wave; LDS transpose; coalesced
// panel write (4096 u32 contiguous).
__global__ __launch_bounds__(1024) void ln_emb_k(
    const int* __restrict__ seqs, const float* __restrict__ iemb,
    const float* __restrict__ pemb,
    const float* __restrict__ g, const float* __restrict__ b,
    float* __restrict__ Xf, u32* __restrict__ OutP, const float* __restrict__ Dv)
{
  __shared__ u32 sh[16][256];
  int w = threadIdx.x >> 6, lane = threadIdx.x & 63;
  size_t row = (size_t)blockIdx.x*16 + w;
  int id = seqs[row];
  int pos = (int)(row & (SEQ-1));
  float x[4] = {0.f, 0.f, 0.f, 0.f};
  if (id != 0) {
    float4 ev = ((const float4*)(iemb + (size_t)id*HD))[lane];
    float4 pv = ((const float4*)(pemb + (size_t)pos*HD))[lane];
    x[0] = ev.x + pv.x; x[1] = ev.y + pv.y; x[2] = ev.z + pv.z; x[3] = ev.w + pv.w;
  }
  float s = 0.f, s2 = 0.f;
#pragma unroll
  for (int k = 0; k < 4; ++k) { s += x[k]; s2 += x[k]*x[k]; }
#pragma unroll
  for (int off = 32; off > 0; off >>= 1) { s += __shfl_xor(s, off, 64); s2 += __shfl_xor(s2, off, 64); }
  float m = s * (1.f/256.f);
  float var = fmaxf(s2 * (1.f/256.f) - m*m, 0.f);
  float rinv = rsqrtf(var + EPS);
  int c0 = lane*4;
  float nx[4];
#pragma unroll
  for (int k = 0; k < 4; ++k) {
    float u = (x[k] - m) * rinv * g[c0+k] + b[c0+k];
    sh[w][c0+k] = pack32(u);
    nx[k] = x[k] + Dv[c0+k] * u;
  }
  ((float4*)(Xf + row*HD))[lane] = make_float4(nx[0], nx[1], nx[2], nx[3]);
  __syncthreads();
  int t = threadIdx.x;
  int gi = t*4;
  int r16 = (gi >> 3) & 15, k8 = gi >> 7, e = gi & 7;
  uint4 vv = *(const uint4*)&sh[r16][k8*8 + e];
  *(uint4*)(OutP + (size_t)blockIdx.x*4096 + gi) = vv;
}

// ---------------- LayerNorm -> packed P(256) ----------------
__global__ __launch_bounds__(1024) void ln_rows(
    float* __restrict__ Xf, const float* __restrict__ g, const float* __restrict__ b,
    u32* __restrict__ OutP)
{
  __shared__ u32 sh[16][256];
  int w = threadIdx.x >> 6, lane = threadIdx.x & 63;
  size_t row = (size_t)blockIdx.x*16 + w;
  float* xrow = Xf + row*HD;
  float4 xv = ((const float4*)xrow)[lane];
  float x[4] = {xv.x, xv.y, xv.z, xv.w};
  float s = 0.f, s2 = 0.f;
#pragma unroll
  for (int k = 0; k < 4; ++k) { s += x[k]; s2 += x[k]*x[k]; }
#pragma unroll
  for (int off = 32; off > 0; off >>= 1) { s += __shfl_xor(s, off, 64); s2 += __shfl_xor(s2, off, 64); }
  float m = s * (1.f/256.f);
  float var = fmaxf(s2 * (1.f/256.f) - m*m, 0.f);
  float rinv = rsqrtf(var + EPS);
  int c0 = lane*4;
#pragma unroll
  for (int k = 0; k < 4; ++k) {
    float u = (x[k] - m) * rinv * g[c0+k] + b[c0+k];
    sh[w][c0+k] = pack32(u);
  }
  __syncthreads();
  int t = threadIdx.x;
  int gi = t*4;
  int r16 = (gi >> 3) & 15, k8 = gi >> 7, e = gi & 7;
  uint4 vv = *(const uint4*)&sh[r16][k8*8 + e];
  *(uint4*)(OutP + (size_t)blockIdx.x*4096 + gi) = vv;
}

// ---------------- streaming MFMA GEMM: B persistent in LDS, no loop barriers ----------
// out[m,n] = sum_k A[m,k]*W[n,k]. A = packed P(K). W hi/lo planes k-major -> staged
// once to LDS fragment-major. 8 waves; wave streams 2-panel (32-row) iterations over
// its M share. Products: Al*Bh + Ah*Bl + Ah*Bh.
// Block g: mblk = g % nmblk (M slab), cg = g / nmblk (col group). nmblk % 8 == 0 so
// all col-groups of a slab land on one XCD (L2-shared A).
// EPI: 0 = packed P(512) out (for scan); 2 = packed P(256) relu(v+bias);
//      3 = Xf = (Xf + v + bias)*mask(ids);  4 = Xf += v.
template<int EPI, int COLS, int K>
__global__ __launch_bounds__(512) void mgemm(
    const u32* __restrict__ A,
    const u16* __restrict__ BhG, const u16* __restrict__ BlG,
    int nmblk, int ppb,
    float* __restrict__ Xf, u32* __restrict__ Op,
    const float* __restrict__ bias, const int* __restrict__ ids)
{
  constexpr int K8 = K/8, NKS = K/32, CF = COLS/16;
  __shared__ __align__(16) u16 BhL[K8*COLS*8];   // 32 KiB
  __shared__ __align__(16) u16 BlL[K8*COLS*8];   // 32 KiB
  const int tid = threadIdx.x;
  const int lane = tid & 63, w = tid >> 6;
  const int l16 = lane & 15, lhi = lane >> 4;
  const int g = blockIdx.x;
  const int mblk = g % nmblk, cg = g / nmblk;
  const int n0 = cg * COLS;

  // stage B slice (fragment-major: [k8][col][8])
  for (int q = tid; q < K8*COLS; q += 512) {
    int c = q % COLS, k8 = q / COLS;
    *(uint4*)&BhL[q*8] = *(const uint4*)(BhG + (size_t)(n0 + c)*K + k8*8);
    *(uint4*)&BlL[q*8] = *(const uint4*)(BlG + (size_t)(n0 + c)*K + k8*8);
  }
  __syncthreads();

  const int iters = ppb >> 4;
#pragma unroll 1
  for (int it = 0; it < iters; ++it) {
    const int p0 = mblk*ppb + (it << 4) + (w << 1);
    f32x4 acc0[CF] = {}, acc1[CF] = {};
#pragma unroll
    for (int ks = 0; ks < NKS; ++ks) {
      const u32* s0 = A + ((size_t)p0*K8 + ks*4 + lhi)*128 + l16*8;
      const u32* s1 = s0 + (size_t)K8*128;
      uint4 r00 = ((const uint4*)s0)[0], r01 = ((const uint4*)s0)[1];
      uint4 r10 = ((const uint4*)s1)[0], r11 = ((const uint4*)s1)[1];
      union U8 { short8v v; u32 u[4]; };
      U8 ah0, al0, ah1, al1;
      {
        u32 q0=r00.x,q1=r00.y,q2=r00.z,q3=r00.w,q4=r01.x,q5=r01.y,q6=r01.z,q7=r01.w;
        ah0.u[0]=(q0&0xffffu)|(q1<<16); al0.u[0]=(q0>>16)|(q1&0xffff0000u);
        ah0.u[1]=(q2&0xffffu)|(q3<<16); al0.u[1]=(q2>>16)|(q3&0xffff0000u);
        ah0.u[2]=(q4&0xffffu)|(q5<<16); al0.u[2]=(q4>>16)|(q5&0xffff0000u);
        ah0.u[3]=(q6&0xffffu)|(q7<<16); al0.u[3]=(q6>>16)|(q7&0xffff0000u);
      }
      {
        u32 q0=r10.x,q1=r10.y,q2=r10.z,q3=r10.w,q4=r11.x,q5=r11.y,q6=r11.z,q7=r11.w;
        ah1.u[0]=(q0&0xffffu)|(q1<<16); al1.u[0]=(q0>>16)|(q1&0xffff0000u);
        ah1.u[1]=(q2&0xffffu)|(q3<<16); al1.u[1]=(q2>>16)|(q3&0xffff0000u);
        ah1.u[2]=(q4&0xffffu)|(q5<<16); al1.u[2]=(q4>>16)|(q5&0xffff0000u);
        ah1.u[3]=(q6&0xffffu)|(q7<<16); al1.u[3]=(q6>>16)|(q7&0xffff0000u);
      }
      const int bo = ((ks*4 + lhi)*COLS + l16)*8;
#pragma unroll
      for (int cf = 0; cf < CF; ++cf) {
        short8v bh = *(const short8v*)&BhL[bo + cf*128];
        short8v bl = *(const short8v*)&BlL[bo + cf*128];
        f32x4 c0 = acc0[cf];
        c0 = __builtin_amdgcn_mfma_f32_16x16x32_bf16(al0.v, bh, c0, 0, 0, 0);
        c0 = __builtin_amdgcn_mfma_f32_16x16x32_bf16(ah0.v, bl, c0, 0, 0, 0);
        c0 = __builtin_amdgcn_mfma_f32_16x16x32_bf16(ah0.v, bh, c0, 0, 0, 0);
        acc0[cf] = c0;
        f32x4 c1 = acc1[cf];
        c1 = __builtin_amdgcn_mfma_f32_16x16x32_bf16(al1.v, bh, c1, 0, 0, 0);
        c1 = __builtin_amdgcn_mfma_f32_16x16x32_bf16(ah1.v, bl, c1, 0, 0, 0);
        c1 = __builtin_amdgcn_mfma_f32_16x16x32_bf16(ah1.v, bh, c1, 0, 0, 0);
        acc1[cf] = c1;
      }
    }
    // epilogue for panels p0 and p0+1
#pragma unroll
    for (int u = 0; u < 2; ++u) {
      const int p = p0 + u;
      f32x4* ac = u ? acc1 : acc0;
#pragma unroll
      for (int jj = 0; jj < 4; ++jj) {
        const int r16 = lhi*4 + jj;
        const int row = p*16 + r16;
        int idv = 0;
        if (EPI == 3) idv = ids[row];
#pragma unroll
        for (int cf = 0; cf < CF; ++cf) {
          const int col = n0 + cf*16 + l16;
          float v = ac[cf][jj];
          if (EPI == 0) {
            Op[((size_t)(p*64 + (col >> 3))*16 + r16)*8 + (col & 7)] = pack32(v);
          } else if (EPI == 2) {
            float tv = fmaxf(v + bias[col], 0.f);
            Op[((size_t)(p*32 + (col >> 3))*16 + r16)*8 + (col & 7)] = pack32(tv);
          } else if (EPI == 3) {
            size_t idx = (size_t)row*HD + col;
            float tv = Xf[idx] + v + bias[col];
            Xf[idx] = (idv != 0) ? tv : 0.f;
          } else {
            size_t idx = (size_t)row*HD + col;
            Xf[idx] = Xf[idx] + v;
          }
        }
      }
    }
  }
}

// ---------------- 16-way time-parallel diagonal complex scan, packed P(512) --------
// grid CB*4 (b = blk>>2, sg = blk&3); block 1024 thr = 16 waves; wave w owns
// t in [w*128,(w+1)*128) = panels w*8..w*8+7. Each lane owns column n (and 256+n):
// reads/writes only its own packed u32 slots -> in-place race-free.
template<bool STORE>
__global__ __launch_bounds__(1024) void pscan_k(
    u32* __restrict__ Sp,
    const float* __restrict__ arp, const float* __restrict__ aip,
    float* __restrict__ xlast_r, float* __restrict__ xlast_i)
{
  __shared__ float sR[16][64], sI[16][64];
  int lane = threadIdx.x & 63;
  int w = threadIdx.x >> 6;
  int b = blockIdx.x >> 2;
  int sg = blockIdx.x & 3;
  int n = (sg << 6) | lane;
  float Ar = arp[n], Ai = aip[n];
  float p128r = Ar, p128i = Ai;
#pragma unroll
  for (int i = 0; i < 7; ++i) {
    float nr = p128r*p128r - p128i*p128i, ni = 2.f*p128r*p128i;
    p128r = nr; p128i = ni;
  }
  const int k8r = n >> 3, e = n & 7;
  const int k8i = 32 + k8r;
  u32* base = Sp + (size_t)b*128*8192;          // batch region: 128 panels x 8192 u32

  // phase 1: local scan (panel-batched loads/stores)
  float xr = 0.f, xi = 0.f;
  for (int pl = w*8; pl < w*8 + 8; ++pl) {
    u32* pb = base + (size_t)pl*8192;
    u32 vr_[16], vi_[16];
#pragma unroll
    for (int r = 0; r < 16; ++r) {
      vr_[r] = pb[k8r*128 + r*8 + e];
      vi_[r] = pb[k8i*128 + r*8 + e];
    }
#pragma unroll
    for (int r = 0; r < 16; ++r) {
      float sr = unp32(vr_[r]), si = unp32(vi_[r]);
      float nxr = Ar*xr - Ai*xi + sr;
      float nxi = Ar*xi + Ai*xr + si;
      xr = nxr; xi = nxi;
      if (STORE) { vr_[r] = pack32(xr); vi_[r] = pack32(xi); }
    }
    if (STORE) {
#pragma unroll
      for (int r = 0; r < 16; ++r) {
        pb[k8r*128 + r*8 + e] = vr_[r];
        pb[k8i*128 + r*8 + e] = vi_[r];
      }
    }
  }

  // phase 2: carries
  sR[w][lane] = xr; sI[w][lane] = xi;
  __syncthreads();
  float er = 0.f, ei = 0.f;
  for (int q = 0; q < w; ++q) {
    float tr = p128r*er - p128i*ei + sR[q][lane];
    float ti = p128r*ei + p128i*er + sI[q][lane];
    er = tr; ei = ti;
  }

  if (!STORE) {
    if (w == 15) {
      float fr = p128r*er - p128i*ei + sR[15][lane];
      float fi = p128r*ei + p128i*er + sI[15][lane];
      xlast_r[b*ND + n] = fr; xlast_i[b*ND + n] = fi;
    }
    return;
  }

  // phase 3: x_t += A^{j+1} * E over own chunk (wave 0: E = 0)
  if (w == 0) return;
  float cre = Ar*er - Ai*ei, cie = Ar*ei + Ai*er;
  for (int pl = w*8; pl < w*8 + 8; ++pl) {
    u32* pb = base + (size_t)pl*8192;
    u32 vr_[16], vi_[16];
#pragma unroll
    for (int r = 0; r < 16; ++r) {
      vr_[r] = pb[k8r*128 + r*8 + e];
      vi_[r] = pb[k8i*128 + r*8 + e];
    }
#pragma unroll
    for (int r = 0; r < 16; ++r) {
      float vr = unp32(vr_[r]) + cre;
      float vi = unp32(vi_[r]) + cie;
      vr_[r] = pack32(vr); vi_[r] = pack32(vi);
      float nr = Ar*cre - Ai*cie, ni = Ar*cie + Ai*cre;
      cre = nr; cie = ni;
    }
#pragma unroll
    for (int r = 0; r < 16; ++r) {
      pb[k8r*128 + r*8 + e] = vr_[r];
      pb[k8i*128 + r*8 + e] = vi_[r];
    }
  }
}

// ---------------- block-1 last-position tail ----------------
__global__ __launch_bounds__(256) void ylast_k(
    const float* __restrict__ xr, const float* __restrict__ xi,
    const float* __restrict__ C1, const float* __restrict__ D1,
    const u32* __restrict__ U,                                  // chunk-local HbP P(256)
    const float* __restrict__ Xf, int b0, float* __restrict__ ylr)
{
  int bl = blockIdx.x, h = threadIdx.x;
  __shared__ float sxr[256], sxi[256];
  sxr[h] = xr[bl*256 + h]; sxi[h] = xi[bl*256 + h];
  __syncthreads();
  float acc = 0.f;
  for (int n = 0; n < 256; ++n) {
    acc += C1[(size_t)(h*256 + n)*2] * sxr[n] - C1[(size_t)(h*256 + n)*2 + 1] * sxi[n];
  }
  size_t lrow = (size_t)bl*SEQ + SEQ - 1;
  size_t p = lrow >> 4;                         // r16 = 15
  float uval = unp32(U[((size_t)(p*32 + (h >> 3))*16 + 15)*8 + (h & 7)]);
  size_t gidx = ((size_t)(b0 + bl)*SEQ + SEQ - 1)*HD + h;
  ylr[(b0 + bl)*256 + h] = Xf[gidx] + acc + D1[h] * uval;
}

__device__ __forceinline__ float block_sum256(float v, volatile float* red) {
#pragma unroll
  for (int off = 32; off > 0; off >>= 1) v += __shfl_xor(v, off, 64);
  int w = threadIdx.x >> 6;
  __syncthreads();
  if ((threadIdx.x & 63) == 0) red[w] = v;
  __syncthreads();
  return red[0] + red[1] + red[2] + red[3];
}

__global__ __launch_bounds__(256) void tail_k(
    const float* __restrict__ ylr, const float* __restrict__ g1, const float* __restrict__ bb1,
    const float* __restrict__ W1p, const float* __restrict__ b1p,
    const float* __restrict__ W2p, const float* __restrict__ b2p,
    const float* __restrict__ fg, const float* __restrict__ fb,
    const int* __restrict__ seqs, float* __restrict__ xfin)
{
  __shared__ float sh[256];
  __shared__ float red[4];
  int b = blockIdx.x, h = threadIdx.x;
  float x = ylr[b*256 + h];
  float m = block_sum256(x, red) * (1.f/256.f);
  float d = x - m;
  float var = fmaxf(block_sum256(d*d, red) * (1.f/256.f), 0.f);
  float h2 = d * rsqrtf(var + EPS) * g1[h] + bb1[h];
  __syncthreads();
  sh[h] = h2;
  __syncthreads();
  float acc = 0.f;
  for (int k = 0; k < 256; ++k) acc += sh[k] * W1p[k*256 + h];
  float f = fmaxf(acc + b1p[h], 0.f);
  __syncthreads();
  sh[h] = f;
  __syncthreads();
  acc = 0.f;
  for (int k = 0; k < 256; ++k) acc += sh[k] * W2p[k*256 + h];
  float x2 = x + acc + b2p[h];
  if (seqs[b*SEQ + SEQ - 1] == 0) x2 = 0.f;
  float m2 = block_sum256(x2, red) * (1.f/256.f);
  float d2 = x2 - m2;
  float v2 = fmaxf(block_sum256(d2*d2, red) * (1.f/256.f), 0.f);
  xfin[b*256 + h] = d2 * rsqrtf(v2 + EPS) * fg[h] + fb[h];
}

// NOTE: reference output dtype is float32 -> d_out is float*.
__global__ __launch_bounds__(256) void logits_k(
    const float* __restrict__ xfin, const int* __restrict__ cand,
    const float* __restrict__ iemb, float* __restrict__ out)
{
  int gid = blockIdx.x*4 + (threadIdx.x >> 6);
  if (gid >= BSZ*NCAND) return;
  int lane = threadIdx.x & 63;
  int b = gid / NCAND;
  int id = cand[gid];
  const float* e  = iemb + (size_t)id*HD;
  const float* xv = xfin + b*256;
  float acc = 0.f;
#pragma unroll
  for (int k = 0; k < 4; ++k) acc += xv[lane*4 + k] * e[lane*4 + k];
#pragma unroll
  for (int off = 32; off > 0; off >>= 1) acc += __shfl_xor(acc, off, 64);
  if (lane == 0) out[gid] = acc;
}

// ---------------- launch ----------------
extern "C" void kernel_launch(void* const* d_in, const int* in_sizes, int n_in,
                              void* d_out, int out_size, void* d_ws, size_t ws_size,
                              hipStream_t stream)
{
  const int*   seqs  = (const int*)d_in[0];
  const int*   cand  = (const int*)d_in[1];
  const float* iemb  = (const float*)d_in[2];
  const float* pemb  = (const float*)d_in[3];
  const float* ln_g  = (const float*)d_in[4];
  const float* ln_b  = (const float*)d_in[5];
  const float* lar   = (const float*)d_in[6];
  const float* aim   = (const float*)d_in[7];
  const float* Bssm  = (const float*)d_in[8];
  const float* Cssm  = (const float*)d_in[9];
  const float* Dssm  = (const float*)d_in[10];
  const float* lstep = (const float*)d_in[11];
  const float* W1    = (const float*)d_in[12];
  const float* b1    = (const float*)d_in[13];
  const float* W2    = (const float*)d_in[14];
  const float* b2    = (const float*)d_in[15];
  const float* lnfg  = (const float*)d_in[16];
  const float* lnfb  = (const float*)d_in[17];

  char* ws = (char*)d_ws;
  float* Xf   = (float*)(ws + OFF_X);
  float* pr   = (float*)(ws + OFF_PR);
  u16*   wb   = (u16*)  (ws + OFF_WB);
  float* xlr  = (float*)(ws + OFF_XLR);
  float* xli  = (float*)(ws + OFF_XLI);
  float* ylr  = (float*)(ws + OFF_YL);
  float* xfin = (float*)(ws + OFF_XF);

  // chunk sizing: HbP = 2*CB MiB, SbP = 4*CB MiB
  int CB = 64;
  while (CB > 1 && (OFF_CH + (size_t)6*CB*MiB) > ws_size) CB >>= 1;
  u32* HbP = (u32*)(ws + OFF_CH);
  u32* SbP = (u32*)(ws + OFF_CH + (size_t)2*CB*MiB);

  pack_k<<<256, 256, 0, stream>>>(lar, aim, lstep, Cssm, W1, W2, Bssm, pr, wb);

  const int rows = CB*SEQ;
  const int npan = rows / 16;
  const int nm8  = npan / 128;    // ppb = 128, NCG = 8 cases
  const int nm4  = npan / 64;     // ppb = 64,  NCG = 4 cases
  for (int b0 = 0; b0 < BSZ; b0 += CB) {
    float* XfC = Xf + (size_t)b0*SEQ*HD;
    const int* seqC = seqs + (size_t)b0*SEQ;

    // ---- block 0: S4 ----
    ln_emb_k<<<npan, 1024, 0, stream>>>(seqC, iemb, pemb, ln_g, ln_b, XfC, HbP, Dssm);
    mgemm<0,64,256><<<nm8*8, 512, 0, stream>>>(HbP, wb + WB_BB0H, wb + WB_BB0L, nm8, 128,
                                               nullptr, SbP, nullptr, nullptr);
    pscan_k<true><<<CB*4, 1024, 0, stream>>>(SbP, pr, pr+512, nullptr, nullptr);
    mgemm<4,32,512><<<nm8*8, 512, 0, stream>>>(SbP, wb + WB_WSH, wb + WB_WSL, nm8, 128,
                                               XfC, nullptr, nullptr, nullptr);
    // ---- block 0: FFN ----
    ln_rows<<<npan, 1024, 0, stream>>>(XfC, ln_g, ln_b, HbP);
    mgemm<2,64,256><<<nm4*4, 512, 0, stream>>>(HbP, wb + WB_W1H, wb + WB_W1L, nm4, 64,
                                               nullptr, SbP, b1, nullptr);
    mgemm<3,64,256><<<nm4*4, 512, 0, stream>>>(SbP, wb + WB_W2H, wb + WB_W2L, nm4, 64,
                                               XfC, nullptr, b2, seqC);
    // ---- block 1 (only last position needed downstream of the scan) ----
    ln_rows<<<npan, 1024, 0, stream>>>(XfC, ln_g + 256, ln_b + 256, HbP);
    mgemm<0,64,256><<<nm8*8, 512, 0, stream>>>(HbP, wb + WB_BB1H, wb + WB_BB1L, nm8, 128,
                                               nullptr, SbP, nullptr, nullptr);
    pscan_k<false><<<CB*4, 1024, 0, stream>>>(SbP, pr+256, pr+768, xlr + b0*256, xli + b0*256);
    ylast_k<<<CB, 256, 0, stream>>>(xlr + b0*256, xli + b0*256, Cssm + 2*65536, Dssm + 256,
                                    HbP, Xf, b0, ylr);
  }

  tail_k<<<BSZ, 256, 0, stream>>>(ylr, ln_g + 256, ln_b + 256, W1 + 65536, b1 + 256,
                                  W2 + 65536, b2 + 256, lnfg, lnfb, seqs, xfin);
  logits_k<<<(BSZ*NCAND + 3)/4, 256, 0, stream>>>(xfin, cand, iemb, (float*)d_out);
}

// Round 8
// 1646.371 us; speedup vs baseline: 1.4788x; 1.4788x over previous
//
#include <hip/hip_runtime.h>
#include <hip/hip_bf16.h>

// ---------------- problem constants ----------------
#define BSZ 64
#define SEQ 2048
#define HD  256
#define ND  256
#define BS_TOK (BSZ*SEQ)          // 131072 tokens
#define NCAND 101
#define EPS 1e-5f

using bf16 = __hip_bfloat16;
typedef unsigned short u16;
typedef unsigned int   u32;
typedef __attribute__((ext_vector_type(8))) short short8v;   // 8 bf16 (4 VGPRs)
typedef __attribute__((ext_vector_type(4))) float f32x4;

__device__ __forceinline__ float clampf(float v, float c) { return fminf(fmaxf(v, -c), c); }

// fp32 -> (hi,lo) bf16 split: x ~= hi + lo to ~2^-17 rel
__device__ __forceinline__ void split_bf(float x, u16& h, u16& l) {
  u32 u = __float_as_uint(x);
  h = (u16)(u >> 16);
  float d = x - __uint_as_float(u & 0xffff0000u);
  l = (u16)(__float_as_uint(d) >> 16);
}
__device__ __forceinline__ float comb_bf(u16 h, u16 l) {
  return __uint_as_float((u32)h << 16) + __uint_as_float((u32)l << 16);
}

// async 16B global->LDS (wave-uniform LDS base + lane*16)
__device__ __forceinline__ void async_copy16(const void* g, void* l) {
  __builtin_amdgcn_global_load_lds(
      (const __attribute__((address_space(1))) void*)g,
      (__attribute__((address_space(3))) void*)l, 16, 0, 0);
}

// Activation plane layout: per row of K logical cols, row stride = 2K u16.
// 64-col group gg occupies u16 [gg*128, gg*128+128): [hi 64 | lo 64],
// 8-u16 chunks XOR-swizzled by row&7 within each half.
// elem (row,k): hi at row*2K + (k>>6)*128 + (((k>>3)&7 ^ row&7)<<3) + (k&7); lo +64.

// ---------------- workspace layout ----------------
static constexpr size_t MiB = 1024*1024;
static constexpr size_t OFF_X    = 0;                         // Xf fp32 [BS_TOK,256]
static constexpr size_t OFF_PR   = 128*MiB;                   // fp32[1024]: abr[512] abi[512]
static constexpr size_t OFF_WB   = OFF_PR + 4096;             // u16 planes, 2 MiB used
static constexpr size_t OFF_XLR  = OFF_WB + 4*MiB;
static constexpr size_t OFF_XLI  = OFF_XLR + 65536;
static constexpr size_t OFF_YL   = OFF_XLI + 65536;
static constexpr size_t OFF_XF   = OFF_YL  + 65536;
static constexpr size_t OFF_CH   = 136*MiB;                   // Hb planes 2*CB MiB, Sb 4*CB MiB

// wb u16 offsets (hi/lo planes, k-major per output col)
static constexpr int WB_BB0H = 0,       WB_BB0L = 131072;     // [512 cols][K=256]
static constexpr int WB_BB1H = 262144,  WB_BB1L = 393216;
static constexpr int WB_WSH  = 524288,  WB_WSL  = 655360;     // [256 cols][K=512]
static constexpr int WB_W1H  = 786432,  WB_W1L  = 851968;     // [256 cols][K=256]
static constexpr int WB_W2H  = 917504,  WB_W2L  = 983040;

// ---------------- param pack ----------------
__global__ __launch_bounds__(256) void pack_k(
    const float* __restrict__ lar, const float* __restrict__ aim, const float* __restrict__ lstep,
    const float* __restrict__ C0, const float* __restrict__ W1, const float* __restrict__ W2,
    const float* __restrict__ Bf,
    float* __restrict__ pr, u16* __restrict__ wb)
{
  int gid = blockIdx.x*256 + threadIdx.x;   // grid 256 -> 65536
  if (gid < 512) {
    int blk = gid >> 8;
    float step = expf(clampf(lstep[blk], 10.f));
    float ar = -expf(clampf(lar[gid], 20.f));
    float ai = aim[gid];
    float er = expf(fminf(ar*step, 0.f));
    pr[gid]       = er * cosf(ai*step);
    pr[512 + gid] = er * sinf(ai*step);
  }
  int r = gid >> 8, c = gid & 255;          // r = out col (n or h), c = k index
  u16 h, l;
#pragma unroll
  for (int blk = 0; blk < 2; ++blk) {
    float step = expf(clampf(lstep[blk], 10.f));
    float ar = -expf(clampf(lar[blk*256 + c], 20.f));
    float ai = aim[blk*256 + c];
    float er  = expf(fminf(ar*step, 0.f));
    float abr = er * cosf(ai*step);
    float abi = er * sinf(ai*step);
    float den = ar*ar + ai*ai;
    float tr = abr - 1.f, ti = abi;
    float cr = (tr*ar + ti*ai) / den;
    float ci = (ti*ar - tr*ai) / den;
    float bv = Bf[blk*65536 + r*256 + c];
    u16* Bh = wb + (blk ? WB_BB1H : WB_BB0H);
    u16* Bl = wb + (blk ? WB_BB1L : WB_BB0L);
    split_bf(cr * bv, h, l); Bh[r*256 + c] = h;         Bl[r*256 + c] = l;
    split_bf(ci * bv, h, l); Bh[(256+r)*256 + c] = h;   Bl[(256+r)*256 + c] = l;
  }
  // Wstk: out col = h (r), k = [n | 256+n], K=512
  split_bf( C0[(size_t)(r*256 + c)*2    ], h, l);
  wb[WB_WSH + r*512 + c] = h;        wb[WB_WSL + r*512 + c] = l;
  split_bf(-C0[(size_t)(r*256 + c)*2 + 1], h, l);
  wb[WB_WSH + r*512 + 256 + c] = h;  wb[WB_WSL + r*512 + 256 + c] = l;
  // W1T/W2T: out col = n (r), k = c
  split_bf(W1[c*256 + r], h, l); wb[WB_W1H + r*256 + c] = h; wb[WB_W1L + r*256 + c] = l;
  split_bf(W2[c*256 + r], h, l); wb[WB_W2H + r*256 + c] = h; wb[WB_W2L + r*256 + c] = l;
}

// ---------------- plane-store helper for LN-type kernels ----------------
// writes 4 consecutive cols (c0 = lane*4) of one row into hi/lo planes
__device__ __forceinline__ void store4_planes(u16* rowp, int lane, int rb7,
                                              float a, float b, float c, float d) {
  int idx = ((lane >> 4) << 7) + (((((lane & 15) >> 1)) ^ rb7) << 3) + ((lane & 1) << 2);
  u16 h0,l0,h1,l1,h2,l2,h3,l3;
  split_bf(a, h0, l0); split_bf(b, h1, l1); split_bf(c, h2, l2); split_bf(d, h3, l3);
  *(uint2*)(rowp + idx)      = make_uint2((u32)h0 | ((u32)h1 << 16), (u32)h2 | ((u32)h3 << 16));
  *(uint2*)(rowp + idx + 64) = make_uint2((u32)l0 | ((u32)l1 << 16), (u32)l2 | ((u32)l3 << 16));
}

// ---------------- fused embed + first LayerNorm (+ D*u residual) ----------------
__global__ __launch_bounds__(256) void ln_emb_k(
    const int* __restrict__ seqs, const float* __restrict__ iemb,
    const float* __restrict__ pemb,
    const float* __restrict__ g, const float* __restrict__ b,
    float* __restrict__ Xf, u16* __restrict__ OutP, const float* __restrict__ Dv)
{
  int w = threadIdx.x >> 6, lane = threadIdx.x & 63;
  size_t row = (size_t)blockIdx.x * 4 + w;
  int id = seqs[row];
  int pos = (int)(row & (SEQ-1));
  float x[4] = {0.f, 0.f, 0.f, 0.f};
  if (id != 0) {
    float4 ev = ((const float4*)(iemb + (size_t)id*HD))[lane];
    float4 pv = ((const float4*)(pemb + (size_t)pos*HD))[lane];
    x[0] = ev.x + pv.x; x[1] = ev.y + pv.y; x[2] = ev.z + pv.z; x[3] = ev.w + pv.w;
  }
  float s = 0.f, s2 = 0.f;
#pragma unroll
  for (int k = 0; k < 4; ++k) { s += x[k]; s2 += x[k]*x[k]; }
#pragma unroll
  for (int off = 32; off > 0; off >>= 1) { s += __shfl_xor(s, off, 64); s2 += __shfl_xor(s2, off, 64); }
  float m = s * (1.f/256.f);
  float var = fmaxf(s2 * (1.f/256.f) - m*m, 0.f);
  float rinv = rsqrtf(var + EPS);
  int c0 = lane*4;
  float u[4], nx[4];
#pragma unroll
  for (int k = 0; k < 4; ++k) {
    u[k] = (x[k] - m) * rinv * g[c0+k] + b[c0+k];
    nx[k] = x[k] + Dv[c0+k] * u[k];
  }
  store4_planes(OutP + row*512, lane, (int)(row & 7), u[0], u[1], u[2], u[3]);
  ((float4*)(Xf + row*HD))[lane] = make_float4(nx[0], nx[1], nx[2], nx[3]);
}

// ---------------- LayerNorm (1 wave per row) -> plane output ----------------
__global__ __launch_bounds__(256) void ln_rows(
    float* __restrict__ Xf, const float* __restrict__ g, const float* __restrict__ b,
    u16* __restrict__ OutP)
{
  int w = threadIdx.x >> 6, lane = threadIdx.x & 63;
  size_t row = (size_t)blockIdx.x * 4 + w;
  float* xrow = Xf + row*HD;
  float4 xv = ((const float4*)xrow)[lane];
  float x[4] = {xv.x, xv.y, xv.z, xv.w};
  float s = 0.f, s2 = 0.f;
#pragma unroll
  for (int k = 0; k < 4; ++k) { s += x[k]; s2 += x[k]*x[k]; }
#pragma unroll
  for (int off = 32; off > 0; off >>= 1) { s += __shfl_xor(s, off, 64); s2 += __shfl_xor(s2, off, 64); }
  float m = s * (1.f/256.f);
  float var = fmaxf(s2 * (1.f/256.f) - m*m, 0.f);
  float rinv = rsqrtf(var + EPS);
  int c0 = lane*4;
  float u[4];
#pragma unroll
  for (int k = 0; k < 4; ++k) u[k] = (x[k] - m) * rinv * g[c0+k] + b[c0+k];
  store4_planes(OutP + row*512, lane, (int)(row & 7), u[0], u[1], u[2], u[3]);
}

// ---------------- 3-term split MFMA GEMM, double-buffered async staging ----------------
// (round-5 structure: 4 waves, 128x128 tile, BK=64 — best measured)
// EPI: 0 = Of[row*ldo+col] = v (fp32);  4 = Xf += v
template<int EPI, int CB_N>
__global__ __launch_bounds__(256) void mgemm(
    const u16* __restrict__ A, int ldp,
    const u16* __restrict__ Bh, const u16* __restrict__ Bl, int K, int ldo,
    float* __restrict__ Xf, float* __restrict__ Of, u16* __restrict__ Op,
    const float* __restrict__ bias, const int* __restrict__ ids)
{
  __shared__ __align__(16) u16 As[2][16384];    // 2 x 32 KiB: [row 0..127][hi 64 | lo 64]
  const int tid  = threadIdx.x;
  const int lane = tid & 63, wid = tid >> 6;
  const int wr = wid >> 1, wc = wid & 1;
  const int l16 = lane & 15, lhi = lane >> 4;
  int g = blockIdx.x;
  int xx = g & 7, j = g >> 3;
  int cb = j % CB_N, rbk = j / CB_N;
  const int m0 = (rbk*8 + xx) * 128;
  const int n0 = cb*128 + wc*64;
  f32x4 acc[4][4] = {};

  auto stage = [&](int buf, int kb) {
    const int ggo = (kb >> 6) << 7;             // group offset in u16
#pragma unroll
    for (int i = 0; i < 8; ++i) {
      int q = wid*8 + i;                        // wave-call 0..31
      int ch = q*64 + lane;                     // chunk 0..2047
      int rr = ch >> 4, jj = ch & 15;
      const u16* src = A + (size_t)(m0 + rr)*ldp + ggo + jj*8;
      async_copy16(src, &As[buf][q*512]);
    }
  };

  stage(0, 0);
  __syncthreads();
  int cur = 0;
  for (int kb = 0; kb < K; kb += 64) {
    if (kb + 64 < K) stage(cur ^ 1, kb + 64);
#pragma unroll
    for (int kk = 0; kk < 64; kk += 32) {
      short8v ahf[4], alf[4];
      const int c8 = (kk >> 3) + lhi;
#pragma unroll
      for (int rf = 0; rf < 4; ++rf) {
        int r = wr*64 + rf*16 + l16;
        int off = r*128 + ((c8 ^ (r & 7)) << 3);
        ahf[rf] = *(const short8v*)&As[cur][off];
        alf[rf] = *(const short8v*)&As[cur][off + 64];
      }
#pragma unroll
      for (int nf = 0; nf < 4; ++nf) {
        size_t bo = (size_t)(n0 + nf*16 + l16)*K + kb + kk + lhi*8;
        short8v bh = *(const short8v*)(Bh + bo);
        short8v bl = *(const short8v*)(Bl + bo);
#pragma unroll
        for (int rf = 0; rf < 4; ++rf) {
          f32x4 c = acc[rf][nf];
          c = __builtin_amdgcn_mfma_f32_16x16x32_bf16(alf[rf], bh, c, 0, 0, 0);
          c = __builtin_amdgcn_mfma_f32_16x16x32_bf16(ahf[rf], bl, c, 0, 0, 0);
          c = __builtin_amdgcn_mfma_f32_16x16x32_bf16(ahf[rf], bh, c, 0, 0, 0);
          acc[rf][nf] = c;
        }
      }
    }
    __syncthreads();
    cur ^= 1;
  }
#pragma unroll
  for (int rf = 0; rf < 4; ++rf) {
#pragma unroll
    for (int jj = 0; jj < 4; ++jj) {
      int row = m0 + wr*64 + rf*16 + lhi*4 + jj;
      int rb7 = row & 7;
      int idv = 0;
      if (EPI == 3) idv = ids[row];
#pragma unroll
      for (int nf = 0; nf < 4; ++nf) {
        int col = n0 + nf*16 + l16;
        float v = acc[rf][nf][jj];
        if (EPI == 0) {
          Of[(size_t)row*ldo + col] = v;
        } else if (EPI == 2) {
          float t = fmaxf(v + bias[col], 0.f);
          u16 hh, ll; split_bf(t, hh, ll);
          size_t base = (size_t)row*ldo + ((col >> 6) << 7)
                      + ((((col >> 3) & 7) ^ rb7) << 3) + (col & 7);
          Op[base] = hh; Op[base + 64] = ll;
        } else if (EPI == 3) {
          size_t idx = (size_t)row*ldo + col;
          float t = Xf[idx] + v + bias[col];
          Xf[idx] = (idv != 0) ? t : 0.f;
        } else {
          size_t idx = (size_t)row*ldo + col;
          Xf[idx] = Xf[idx] + v;
        }
      }
    }
  }
}

// ---------------- fused FFN: Xf = mask * (Xf + relu(A@W1+b1)@W2 + b2) ----------------
// 32-row x 256-col block, 8 waves. A (Hb planes, ldp=512) staged once by DMA (32 KiB);
// T = relu(A@W1+b1) held in LDS as hi/lo planes (32 KiB, same numerics as the unfused
// path); phase 2 multiplies T@W2 from LDS. W1/W2 fragments read from global (L2-hot).
// Wave w: rows 0..31 (rf 0..1), cols w*32 + cf*16 (cf 0..1).
__global__ __launch_bounds__(512) void ffn_k(
    const u16* __restrict__ A,
    const u16* __restrict__ W1h, const u16* __restrict__ W1l,
    const u16* __restrict__ W2h, const u16* __restrict__ W2l,
    const float* __restrict__ b1p, const float* __restrict__ b2p,
    float* __restrict__ Xf, const int* __restrict__ ids)
{
  __shared__ __align__(16) u16 As[16384];   // 32 rows x 512 u16 (plane layout)
  __shared__ __align__(16) u16 Ts[16384];
  const int tid = threadIdx.x;
  const int lane = tid & 63, w = tid >> 6;
  const int l16 = lane & 15, lhi = lane >> 4;
  const int m0 = blockIdx.x * 32;

  // stage A: each wave-call stages one full row (64 lanes x 16 B = 1 KiB)
#pragma unroll
  for (int i = 0; i < 4; ++i) {
    int rr = i*8 + w;
    async_copy16(A + (size_t)(m0 + rr)*512 + lane*8, &As[rr*512]);
  }
  __syncthreads();

  // ---- phase 1: T = relu(A@W1 + b1) ----
  f32x4 acc[2][2] = {};
#pragma unroll
  for (int ks = 0; ks < 8; ++ks) {
    const int kk = ks*32;
    const int c8g = (kk >> 3) + lhi;
    const int gg = c8g >> 3, cg = c8g & 7;
    short8v ahf[2], alf[2];
#pragma unroll
    for (int rf = 0; rf < 2; ++rf) {
      int r = rf*16 + l16;
      int off = r*512 + gg*128 + ((cg ^ (r & 7)) << 3);
      ahf[rf] = *(const short8v*)&As[off];
      alf[rf] = *(const short8v*)&As[off + 64];
    }
#pragma unroll
    for (int cf = 0; cf < 2; ++cf) {
      size_t bo = (size_t)(w*32 + cf*16 + l16)*256 + kk + lhi*8;
      short8v bh = *(const short8v*)(W1h + bo);
      short8v bl = *(const short8v*)(W1l + bo);
#pragma unroll
      for (int rf = 0; rf < 2; ++rf) {
        f32x4 c = acc[rf][cf];
        c = __builtin_amdgcn_mfma_f32_16x16x32_bf16(alf[rf], bh, c, 0, 0, 0);
        c = __builtin_amdgcn_mfma_f32_16x16x32_bf16(ahf[rf], bl, c, 0, 0, 0);
        c = __builtin_amdgcn_mfma_f32_16x16x32_bf16(ahf[rf], bh, c, 0, 0, 0);
        acc[rf][cf] = c;
      }
    }
  }
  // write T planes into LDS (bias + relu + split)
#pragma unroll
  for (int rf = 0; rf < 2; ++rf) {
#pragma unroll
    for (int jj = 0; jj < 4; ++jj) {
      int row = rf*16 + lhi*4 + jj;
      int rb7 = row & 7;
#pragma unroll
      for (int cf = 0; cf < 2; ++cf) {
        int col = w*32 + cf*16 + l16;
        float t = fmaxf(acc[rf][cf][jj] + b1p[col], 0.f);
        u16 hh, ll; split_bf(t, hh, ll);
        int base = row*512 + ((col >> 6) << 7) + ((((col >> 3) & 7) ^ rb7) << 3) + (col & 7);
        Ts[base] = hh; Ts[base + 64] = ll;
      }
    }
  }
  __syncthreads();

  // ---- phase 2: O = T@W2 + b2; Xf RMW with mask ----
  f32x4 acc2[2][2] = {};
#pragma unroll
  for (int ks = 0; ks < 8; ++ks) {
    const int kk = ks*32;
    const int c8g = (kk >> 3) + lhi;
    const int gg = c8g >> 3, cg = c8g & 7;
    short8v ahf[2], alf[2];
#pragma unroll
    for (int rf = 0; rf < 2; ++rf) {
      int r = rf*16 + l16;
      int off = r*512 + gg*128 + ((cg ^ (r & 7)) << 3);
      ahf[rf] = *(const short8v*)&Ts[off];
      alf[rf] = *(const short8v*)&Ts[off + 64];
    }
#pragma unroll
    for (int cf = 0; cf < 2; ++cf) {
      size_t bo = (size_t)(w*32 + cf*16 + l16)*256 + kk + lhi*8;
      short8v bh = *(const short8v*)(W2h + bo);
      short8v bl = *(const short8v*)(W2l + bo);
#pragma unroll
      for (int rf = 0; rf < 2; ++rf) {
        f32x4 c = acc2[rf][cf];
        c = __builtin_amdgcn_mfma_f32_16x16x32_bf16(alf[rf], bh, c, 0, 0, 0);
        c = __builtin_amdgcn_mfma_f32_16x16x32_bf16(ahf[rf], bl, c, 0, 0, 0);
        c = __builtin_amdgcn_mfma_f32_16x16x32_bf16(ahf[rf], bh, c, 0, 0, 0);
        acc2[rf][cf] = c;
      }
    }
  }
#pragma unroll
  for (int rf = 0; rf < 2; ++rf) {
#pragma unroll
    for (int jj = 0; jj < 4; ++jj) {
      int row = m0 + rf*16 + lhi*4 + jj;
      int idv = ids[row];
#pragma unroll
      for (int cf = 0; cf < 2; ++cf) {
        int col = w*32 + cf*16 + l16;
        size_t idx = (size_t)row*HD + col;
        float t = Xf[idx] + acc2[rf][cf][jj] + b2p[col];
        Xf[idx] = (idv != 0) ? t : 0.f;
      }
    }
  }
}

// ---------------- 16-way time-parallel diagonal complex scan ----------------
template<bool STORE>
__global__ __launch_bounds__(1024) void pscan_k(
    float* __restrict__ Sb,
    const float* __restrict__ arp, const float* __restrict__ aip,
    float* __restrict__ xlast_r, float* __restrict__ xlast_i)
{
  __shared__ float sR[16][64], sI[16][64];
  int lane = threadIdx.x & 63;
  int w = threadIdx.x >> 6;
  int b = blockIdx.x >> 2;
  int sg = blockIdx.x & 3;
  int n = (sg << 6) | lane;
  float Ar = arp[n], Ai = aip[n];
  float p128r = Ar, p128i = Ai;
#pragma unroll
  for (int i = 0; i < 7; ++i) {
    float nr = p128r*p128r - p128i*p128i, ni = 2.f*p128r*p128i;
    p128r = nr; p128i = ni;
  }
  const int t0 = w*128;
  const float* sp = Sb + ((size_t)b*SEQ + t0)*512 + n;
  u16* qp16 = (u16*)(Sb + (size_t)b*SEQ*512);
  const int sgo = sg << 7;
  const int lo3 = lane & 7, lh3 = lane >> 3;

  float xr = 0.f, xi = 0.f;
#pragma unroll 4
  for (int t = 0; t < 128; ++t) {
    float sr = sp[0], si = sp[256];
    float nxr = Ar*xr - Ai*xi + sr;
    float nxi = Ar*xi + Ai*xr + si;
    xr = nxr; xi = nxi;
    if (STORE) {
      int tt = t0 + t;
      size_t si2 = (size_t)tt*1024 + sgo + (((lh3 ^ (tt & 7))) << 3) + lo3;
      u16 hh, ll;
      split_bf(xr, hh, ll); qp16[si2] = hh;       qp16[si2 + 64]  = ll;
      split_bf(xi, hh, ll); qp16[si2 + 512] = hh; qp16[si2 + 576] = ll;
    }
    sp += 512;
  }

  sR[w][lane] = xr; sI[w][lane] = xi;
  __syncthreads();
  float er = 0.f, ei = 0.f;
  for (int q = 0; q < w; ++q) {
    float tr = p128r*er - p128i*ei + sR[q][lane];
    float ti = p128r*ei + p128i*er + sI[q][lane];
    er = tr; ei = ti;
  }

  if (!STORE) {
    if (w == 15) {
      float fr = p128r*er - p128i*ei + sR[15][lane];
      float fi = p128r*ei + p128i*er + sI[15][lane];
      xlast_r[b*ND + n] = fr; xlast_i[b*ND + n] = fi;
    }
    return;
  }

  if (w == 0) return;
  float cr = Ar*er - Ai*ei, ci = Ar*ei + Ai*er;
#pragma unroll 4
  for (int t = 0; t < 128; ++t) {
    int tt = t0 + t;
    size_t si2 = (size_t)tt*1024 + sgo + (((lh3 ^ (tt & 7))) << 3) + lo3;
    float vr = comb_bf(qp16[si2],       qp16[si2 + 64])  + cr;
    float vi = comb_bf(qp16[si2 + 512], qp16[si2 + 576]) + ci;
    u16 hh, ll;
    split_bf(vr, hh, ll); qp16[si2] = hh;       qp16[si2 + 64]  = ll;
    split_bf(vi, hh, ll); qp16[si2 + 512] = hh; qp16[si2 + 576] = ll;
    float nr = Ar*cr - Ai*ci, ni = Ar*ci + Ai*cr;
    cr = nr; ci = ni;
  }
}

// ---------------- block-1 last-position tail ----------------
__global__ __launch_bounds__(256) void ylast_k(
    const float* __restrict__ xr, const float* __restrict__ xi,
    const float* __restrict__ C1, const float* __restrict__ D1,
    const u16* __restrict__ U,                                  // chunk-local Hb planes
    const float* __restrict__ Xf, int b0, float* __restrict__ ylr)
{
  int bl = blockIdx.x, h = threadIdx.x;
  __shared__ float sxr[256], sxi[256];
  sxr[h] = xr[bl*256 + h]; sxi[h] = xi[bl*256 + h];
  __syncthreads();
  float acc = 0.f;
  for (int n = 0; n < 256; ++n) {
    acc += C1[(size_t)(h*256 + n)*2] * sxr[n] - C1[(size_t)(h*256 + n)*2 + 1] * sxi[n];
  }
  size_t lrow = (size_t)bl*SEQ + SEQ - 1;     // (lrow&7)==7
  size_t ub = lrow*512 + ((h >> 6) << 7) + ((((h >> 3) & 7) ^ 7) << 3) + (h & 7);
  float uval = comb_bf(U[ub], U[ub + 64]);
  size_t gidx = ((size_t)(b0 + bl)*SEQ + SEQ - 1)*HD + h;
  ylr[(b0 + bl)*256 + h] = Xf[gidx] + acc + D1[h] * uval;
}

__device__ __forceinline__ float block_sum256(float v, volatile float* red) {
#pragma unroll
  for (int off = 32; off > 0; off >>= 1) v += __shfl_xor(v, off, 64);
  int w = threadIdx.x >> 6;
  __syncthreads();
  if ((threadIdx.x & 63) == 0) red[w] = v;
  __syncthreads();
  return red[0] + red[1] + red[2] + red[3];
}

__global__ __launch_bounds__(256) void tail_k(
    const float* __restrict__ ylr, const float* __restrict__ g1, const float* __restrict__ bb1,
    const float* __restrict__ W1p, const float* __restrict__ b1p,
    const float* __restrict__ W2p, const float* __restrict__ b2p,
    const float* __restrict__ fg, const float* __restrict__ fb,
    const int* __restrict__ seqs, float* __restrict__ xfin)
{
  __shared__ float sh[256];
  __shared__ float red[4];
  int b = blockIdx.x, h = threadIdx.x;
  float x = ylr[b*256 + h];
  float m = block_sum256(x, red) * (1.f/256.f);
  float d = x - m;
  float var = fmaxf(block_sum256(d*d, red) * (1.f/256.f), 0.f);
  float h2 = d * rsqrtf(var + EPS) * g1[h] + bb1[h];
  __syncthreads();
  sh[h] = h2;
  __syncthreads();
  float acc = 0.f;
  for (int k = 0; k < 256; ++k) acc += sh[k] * W1p[k*256 + h];
  float f = fmaxf(acc + b1p[h], 0.f);
  __syncthreads();
  sh[h] = f;
  __syncthreads();
  acc = 0.f;
  for (int k = 0; k < 256; ++k) acc += sh[k] * W2p[k*256 + h];
  float x2 = x + acc + b2p[h];
  if (seqs[b*SEQ + SEQ - 1] == 0) x2 = 0.f;
  float m2 = block_sum256(x2, red) * (1.f/256.f);
  float d2 = x2 - m2;
  float v2 = fmaxf(block_sum256(d2*d2, red) * (1.f/256.f), 0.f);
  xfin[b*256 + h] = d2 * rsqrtf(v2 + EPS) * fg[h] + fb[h];
}

// NOTE: reference output dtype is float32 -> d_out is float*.
__global__ __launch_bounds__(256) void logits_k(
    const float* __restrict__ xfin, const int* __restrict__ cand,
    const float* __restrict__ iemb, float* __restrict__ out)
{
  int gid = blockIdx.x*4 + (threadIdx.x >> 6);
  if (gid >= BSZ*NCAND) return;
  int lane = threadIdx.x & 63;
  int b = gid / NCAND;
  int id = cand[gid];
  const float* e  = iemb + (size_t)id*HD;
  const float* xv = xfin + b*256;
  float acc = 0.f;
#pragma unroll
  for (int k = 0; k < 4; ++k) acc += xv[lane*4 + k] * e[lane*4 + k];
#pragma unroll
  for (int off = 32; off > 0; off >>= 1) acc += __shfl_xor(acc, off, 64);
  if (lane == 0) out[gid] = acc;
}

// ---------------- launch ----------------
extern "C" void kernel_launch(void* const* d_in, const int* in_sizes, int n_in,
                              void* d_out, int out_size, void* d_ws, size_t ws_size,
                              hipStream_t stream)
{
  const int*   seqs  = (const int*)d_in[0];
  const int*   cand  = (const int*)d_in[1];
  const float* iemb  = (const float*)d_in[2];
  const float* pemb  = (const float*)d_in[3];
  const float* ln_g  = (const float*)d_in[4];
  const float* ln_b  = (const float*)d_in[5];
  const float* lar   = (const float*)d_in[6];
  const float* aim   = (const float*)d_in[7];
  const float* Bssm  = (const float*)d_in[8];
  const float* Cssm  = (const float*)d_in[9];
  const float* Dssm  = (const float*)d_in[10];
  const float* lstep = (const float*)d_in[11];
  const float* W1    = (const float*)d_in[12];
  const float* b1    = (const float*)d_in[13];
  const float* W2    = (const float*)d_in[14];
  const float* b2    = (const float*)d_in[15];
  const float* lnfg  = (const float*)d_in[16];
  const float* lnfb  = (const float*)d_in[17];

  char* ws = (char*)d_ws;
  float* Xf   = (float*)(ws + OFF_X);
  float* pr   = (float*)(ws + OFF_PR);
  u16*   wb   = (u16*)  (ws + OFF_WB);
  float* xlr  = (float*)(ws + OFF_XLR);
  float* xli  = (float*)(ws + OFF_XLI);
  float* ylr  = (float*)(ws + OFF_YL);
  float* xfin = (float*)(ws + OFF_XF);

  // chunk sizing: Hb planes = 2*CB MiB, Sb = 4*CB MiB
  int CB = 64;
  while (CB > 1 && (OFF_CH + (size_t)6*CB*MiB) > ws_size) CB >>= 1;
  u16*   HbP = (u16*)(ws + OFF_CH);
  float* SbC = (float*)(ws + OFF_CH + (size_t)2*CB*MiB);

  pack_k<<<256, 256, 0, stream>>>(lar, aim, lstep, Cssm, W1, W2, Bssm, pr, wb);

  const int rows = CB*SEQ;
  const int rb   = rows / 128;
  for (int b0 = 0; b0 < BSZ; b0 += CB) {
    float* XfC = Xf + (size_t)b0*SEQ*HD;
    const int* seqC = seqs + (size_t)b0*SEQ;

    // ---- block 0: S4 ----
    ln_emb_k<<<rows/4, 256, 0, stream>>>(seqC, iemb, pemb, ln_g, ln_b, XfC, HbP, Dssm);
    mgemm<0,4><<<4*rb, 256, 0, stream>>>(HbP, 512, wb + WB_BB0H, wb + WB_BB0L, 256, 512,
                                         nullptr, SbC, nullptr, nullptr, nullptr);
    pscan_k<true><<<CB*4, 1024, 0, stream>>>(SbC, pr, pr+512, nullptr, nullptr);
    mgemm<4,2><<<2*rb, 256, 0, stream>>>((u16*)SbC, 1024, wb + WB_WSH, wb + WB_WSL, 512, 256,
                                         XfC, nullptr, nullptr, nullptr, nullptr);
    // ---- block 0: FFN (fused W1+relu+W2) ----
    ln_rows<<<rows/4, 256, 0, stream>>>(XfC, ln_g, ln_b, HbP);
    ffn_k<<<rows/32, 512, 0, stream>>>(HbP, wb + WB_W1H, wb + WB_W1L, wb + WB_W2H, wb + WB_W2L,
                                       b1, b2, XfC, seqC);
    // ---- block 1 (only last position needed downstream of the scan) ----
    ln_rows<<<rows/4, 256, 0, stream>>>(XfC, ln_g + 256, ln_b + 256, HbP);
    mgemm<0,4><<<4*rb, 256, 0, stream>>>(HbP, 512, wb + WB_BB1H, wb + WB_BB1L, 256, 512,
                                         nullptr, SbC, nullptr, nullptr, nullptr);
    pscan_k<false><<<CB*4, 1024, 0, stream>>>(SbC, pr+256, pr+768, xlr + b0*256, xli + b0*256);
    ylast_k<<<CB, 256, 0, stream>>>(xlr + b0*256, xli + b0*256, Cssm + 2*65536, Dssm + 256,
                                    HbP, Xf, b0, ylr);
  }

  tail_k<<<BSZ, 256, 0, stream>>>(ylr, ln_g + 256, ln_b + 256, W1 + 65536, b1 + 256,
                                  W2 + 65536, b2 + 256, lnfg, lnfb, seqs, xfin);
  logits_k<<<(BSZ*NCAND + 3)/4, 256, 0, stream>>>(xfin, cand, iemb, (float*)d_out);
}